// Round 8
// baseline (397.513 us; speedup 1.0000x reference)
//
#include <hip/hip_runtime.h>
#include <hip/hip_bf16.h>

#define NN 8192
#define FF 64
#define JSPLIT 8
#define JRANGE (NN / JSPLIT)    // 1024 cols per block
#define JT 64                   // cols per iteration
#define NIT (JRANGE / JT)       // 16
#define PROW 66                 // partial row stride: H[0..63], l at [64]

// LDS layout per buffer (bytes)
#define B_OFF   0               // B tile: 64 feat-rows x 128 B
#define MK_OFF  8192            // byte-mask tile: 64 rows x 64 B
#define BV_OFF  12288           // B_j factors: 64 fp16 (D_j at +128)
#define DUP_OFF 12544           // dummy slot (uniform load count)
#define BUF_SZ  12800

typedef _Float16 half8 __attribute__((ext_vector_type(8)));
typedef _Float16 half4v __attribute__((ext_vector_type(4)));
typedef _Float16 half2v __attribute__((ext_vector_type(2)));
typedef float f32x4 __attribute__((ext_vector_type(4)));
typedef int i32x4 __attribute__((ext_vector_type(4)));
typedef unsigned char u8x8 __attribute__((ext_vector_type(8)));

__device__ __forceinline__ void async16(const void* g, void* l)
{
    __builtin_amdgcn_global_load_lds(
        (const __attribute__((address_space(1))) unsigned int*)g,
        (__attribute__((address_space(3))) unsigned int*)l, 16, 0, 0);
}
__device__ __forceinline__ void async4(const void* g, void* l)
{
    __builtin_amdgcn_global_load_lds(
        (const __attribute__((address_space(1))) unsigned int*)g,
        (__attribute__((address_space(3))) unsigned int*)l, 4, 0, 0);
}

// ---------------------------------------------------------------------------
// Kernel 0: adj (256 MB int32 0/1) -> byte mask (67 MB, 0xFF / 0x00).
// Pure streaming, 32 B read + 8 B write per thread.
// ---------------------------------------------------------------------------
__global__ __launch_bounds__(256) void k_pack(const int* __restrict__ adj,
                                              unsigned char* __restrict__ mask)
{
    const size_t idx = (size_t)blockIdx.x * 256 + threadIdx.x;   // 8-col group
    const i32x4* p = (const i32x4*)adj + idx * 2;
    i32x4 a = __builtin_nontemporal_load(p);
    i32x4 b = __builtin_nontemporal_load(p + 1);
    u8x8 v;
    v[0] = (a[0] > 0) ? 0xFF : 0; v[1] = (a[1] > 0) ? 0xFF : 0;
    v[2] = (a[2] > 0) ? 0xFF : 0; v[3] = (a[3] > 0) ? 0xFF : 0;
    v[4] = (b[0] > 0) ? 0xFF : 0; v[5] = (b[1] > 0) ? 0xFF : 0;
    v[6] = (b[2] > 0) ? 0xFF : 0; v[7] = (b[3] > 0) ? 0xFF : 0;
    *(u8x8*)(mask + idx * 8) = v;
}

// ---------------------------------------------------------------------------
// Kernel 1: Wh = inputs @ W; s = Wh@a_src; d = Wh@a_dst; WhT fp16 (64 x NN);
// per-block max(d) partial.
// ---------------------------------------------------------------------------
__global__ __launch_bounds__(256) void k_prep(const float* __restrict__ inp,
                                              const float* __restrict__ W,
                                              const float* __restrict__ a,
                                              _Float16* __restrict__ WhT,
                                              float* __restrict__ s,
                                              float* __restrict__ d,
                                              float* __restrict__ dmax_part)
{
    __shared__ float Wl[64][64];
    __shared__ float asrc[64], adst[64];
    __shared__ _Float16 tr[64][20];
    __shared__ float dmx[16];
    const int t = threadIdx.x;
    for (int idx = t; idx < 4096; idx += 256) Wl[idx >> 6][idx & 63] = W[idx];
    if (t < 64) { asrc[t] = a[t]; adst[t] = a[64 + t]; }
    __syncthreads();

    const int rowl = t >> 4;
    const int fg   = t & 15;
    const int row  = blockIdx.x * 16 + rowl;
    const float* ip = inp + (size_t)row * FF;

    float a0 = 0.f, a1 = 0.f, a2 = 0.f, a3 = 0.f;
    #pragma unroll
    for (int k4 = 0; k4 < 16; ++k4) {
        float4 x  = *(const float4*)(ip + k4 * 4);
        float4 w0 = *(const float4*)&Wl[k4 * 4 + 0][fg * 4];
        float4 w1 = *(const float4*)&Wl[k4 * 4 + 1][fg * 4];
        float4 w2 = *(const float4*)&Wl[k4 * 4 + 2][fg * 4];
        float4 w3 = *(const float4*)&Wl[k4 * 4 + 3][fg * 4];
        a0 += x.x * w0.x + x.y * w1.x + x.z * w2.x + x.w * w3.x;
        a1 += x.x * w0.y + x.y * w1.y + x.z * w2.y + x.w * w3.y;
        a2 += x.x * w0.z + x.y * w1.z + x.z * w2.z + x.w * w3.z;
        a3 += x.x * w0.w + x.y * w1.w + x.z * w2.w + x.w * w3.w;
    }

    float sp = a0 * asrc[fg*4] + a1 * asrc[fg*4+1] + a2 * asrc[fg*4+2] + a3 * asrc[fg*4+3];
    float dp = a0 * adst[fg*4] + a1 * adst[fg*4+1] + a2 * adst[fg*4+2] + a3 * adst[fg*4+3];
    #pragma unroll
    for (int msk = 1; msk < 16; msk <<= 1) {
        sp += __shfl_xor(sp, msk);
        dp += __shfl_xor(dp, msk);
    }
    if (fg == 0) { s[row] = sp; d[row] = dp; dmx[rowl] = dp; }

    tr[fg * 4 + 0][rowl] = (_Float16)a0;
    tr[fg * 4 + 1][rowl] = (_Float16)a1;
    tr[fg * 4 + 2][rowl] = (_Float16)a2;
    tr[fg * 4 + 3][rowl] = (_Float16)a3;
    __syncthreads();
    {
        const int f = t >> 2, seg = t & 3;
        *(half4v*)(WhT + (size_t)f * NN + blockIdx.x * 16 + seg * 4) =
            *(const half4v*)&tr[f][seg * 4];
    }
    if (t == 0) {
        float mm = dmx[0];
        #pragma unroll
        for (int i = 1; i < 16; ++i) mm = fmaxf(mm, dmx[i]);
        dmax_part[blockIdx.x] = mm;
    }
}

// ---------------------------------------------------------------------------
// Kernel 2: dmax; separable softmax factors (all <= 1, fp16-safe):
// A_i=e^{(s_i+dmax)-c_i}, C_i=e^{0.2(s_i+dmax)-c_i},
// B_j=e^{d_j-dmax},       D_j=e^{0.2(d_j-dmax)}.
// ---------------------------------------------------------------------------
__global__ __launch_bounds__(256) void k_vec(const float* __restrict__ s,
                                             const float* __restrict__ d,
                                             const float* __restrict__ dmax_part,
                                             _Float16* __restrict__ afac,
                                             _Float16* __restrict__ cfac,
                                             _Float16* __restrict__ bfac,
                                             _Float16* __restrict__ dfac)
{
    __shared__ float red[256];
    const int t = threadIdx.x;
    float m = fmaxf(dmax_part[t], dmax_part[t + 256]);
    red[t] = m;
    __syncthreads();
    for (int off = 128; off > 0; off >>= 1) {
        if (t < off) red[t] = fmaxf(red[t], red[t + off]);
        __syncthreads();
    }
    const float dmax = red[0];
    const int row = blockIdx.x * 256 + t;
    const float x = s[row] + dmax;
    const float c = fmaxf(x, 0.2f * x);
    afac[row] = (_Float16)__expf(x - c);
    cfac[row] = (_Float16)__expf(0.2f * x - c);
    const float y = d[row] - dmax;
    bfac[row] = (_Float16)__expf(y);
    dfac[row] = (_Float16)__expf(0.2f * y);
}

// ---------------------------------------------------------------------------
// Kernel 3 (main): 1024 blocks = 128 row-tiles(64) x 8 j-splits, 4 blocks/CU.
// Per iter (64 cols): B tile 8 KB + byte-mask 4 KB + B_j/D_j 256 B staged via
// 4 global_load_lds/wave, vmcnt(4) cross-barrier pipeline. Hot loop has NO
// exp: p-pair = (pk_max(A*B, C*D)) & perm-expanded byte mask. Row-sum l via
// 5th MFMA against constant ones fragment.
// ---------------------------------------------------------------------------
__global__ __launch_bounds__(256, 4) void k_main(const unsigned char* __restrict__ mask,
                                                 const _Float16* __restrict__ WhT,
                                                 const _Float16* __restrict__ afac,
                                                 const _Float16* __restrict__ cfac,
                                                 const _Float16* __restrict__ bfac,
                                                 const _Float16* __restrict__ dfac,
                                                 float* __restrict__ part)
{
    __shared__ __align__(16) unsigned char sm[2 * BUF_SZ];

    const int tid  = threadIdx.x;
    const int wv   = tid >> 6;
    const int lane = tid & 63;
    const int mrow = lane & 15;
    const int g    = lane >> 4;
    const int rt   = blockIdx.x & 127;
    const int js   = blockIdx.x >> 7;
    const int i0   = rt * 64;
    const int j0base = js * JRANGE;
    const int arow = i0 + wv * 16 + mrow;
    const int rloc = wv * 16 + mrow;

    // per-row factors -> packed fp16 pairs (uniform per lane)
    union { _Float16 h[2]; unsigned u; half2v v; } ua, uc;
    ua.h[0] = afac[arow]; ua.h[1] = ua.h[0];
    uc.h[0] = cfac[arow]; uc.h[1] = uc.h[0];
    const half2v a2 = ua.v, c2 = uc.v;

    f32x4 acc[5];
    #pragma unroll
    for (int n = 0; n < 5; ++n) acc[n] = (f32x4){0.f, 0.f, 0.f, 0.f};

    // stage tile `it` into buffer b: exactly 4 global_load_lds per wave
    auto stage = [&](int b, int it) {
        const int j0 = j0base + it * JT;
        unsigned char* base = &sm[b * BUF_SZ];
        #pragma unroll
        for (int qq = 0; qq < 2; ++qq) {
            const int q = wv * 2 + qq;
            const int f = q * 8 + (lane >> 3);
            async16(WhT + (size_t)f * NN + j0 + (lane & 7) * 8,
                    base + B_OFF + q * 1024 + lane * 16);
        }
        {   // byte-mask: 16 rows per wave, 64 B per row
            const int r = wv * 16 + (lane >> 2);
            async16(mask + (size_t)(i0 + r) * NN + j0 + (lane & 3) * 16,
                    base + MK_OFF + wv * 1024 + lane * 16);
        }
        {   // B_j / D_j factors (wave 0 real, others to dup slot)
            const _Float16* gsrc = (lane < 32) ? (bfac + j0 + lane * 2)
                                               : (dfac + j0 + (lane - 32) * 2);
            async4(gsrc, base + ((wv == 0) ? BV_OFF : DUP_OFF) + (lane & 63) * 4);
        }
    };

    stage(0, 0);
    asm volatile("s_waitcnt vmcnt(0)" ::: "memory");
    __builtin_amdgcn_s_barrier();

    const half8 ones = {(_Float16)1.f, (_Float16)1.f, (_Float16)1.f, (_Float16)1.f,
                        (_Float16)1.f, (_Float16)1.f, (_Float16)1.f, (_Float16)1.f};

    for (int it = 0; it < NIT; ++it) {
        if (it + 1 < NIT) {
            stage((it + 1) & 1, it + 1);                      // prefetch
            asm volatile("s_waitcnt vmcnt(4)" ::: "memory");  // drain tile(it)
        } else {
            asm volatile("s_waitcnt vmcnt(0)" ::: "memory");
        }
        __builtin_amdgcn_s_barrier();
        asm volatile("" ::: "memory");

        const unsigned char* base = &sm[(it & 1) * BUF_SZ];

        #pragma unroll
        for (int cc = 0; cc < 2; ++cc) {
            uint2 mv  = *(const uint2*)(base + MK_OFF + rloc * 64 + cc * 32 + g * 8);
            uint4 bv4 = *(const uint4*)(base + BV_OFF + cc * 64 + g * 16);
            uint4 dv4 = *(const uint4*)(base + BV_OFF + 128 + cc * 64 + g * 16);

            union { unsigned u[4]; half8 h; } af;
            #pragma unroll
            for (int k = 0; k < 4; ++k) {
                const unsigned w   = (k < 2) ? mv.x : mv.y;
                const unsigned sel = (k & 1) ? 0x03030202u : 0x01010000u;
                const unsigned m32 = __builtin_amdgcn_perm(w, w, sel);
                union { unsigned u; half2v v; } b2, d2, pm;
                b2.u = ((const unsigned*)&bv4)[k];
                d2.u = ((const unsigned*)&dv4)[k];
                pm.v = __builtin_elementwise_max(a2 * b2.v, c2 * d2.v);
                af.u[k] = pm.u & m32;
            }

            #pragma unroll
            for (int n = 0; n < 4; ++n) {
                half8 B = *(const half8*)(base + B_OFF + (n * 16 + mrow) * 128 +
                                          cc * 64 + g * 16);
                acc[n] = __builtin_amdgcn_mfma_f32_16x16x32_f16(af.h, B, acc[n], 0, 0, 0);
            }
            acc[4] = __builtin_amdgcn_mfma_f32_16x16x32_f16(af.h, ones, acc[4], 0, 0, 0);
        }

        if (it + 1 < NIT) {
            asm volatile("" ::: "memory");
            __builtin_amdgcn_s_barrier();   // reads done before next overwrite
        }
    }

    // ---- epilogue: per-wave rows, l already replicated across cols ----
    float* pb = part + (size_t)blockIdx.x * (64 * PROW) + wv * 16 * PROW;
    #pragma unroll
    for (int n = 0; n < 4; ++n)
        #pragma unroll
        for (int r = 0; r < 4; ++r)
            pb[(g * 4 + r) * PROW + n * 16 + mrow] = acc[n][r];
    if (mrow == 0) {
        #pragma unroll
        for (int r = 0; r < 4; ++r)
            pb[(g * 4 + r) * PROW + 64] = acc[4][r];
    }
}

// ---------------------------------------------------------------------------
// Kernel 4: combine 8 j-split partials, divide by l, ELU, write out.
// ---------------------------------------------------------------------------
__global__ __launch_bounds__(256) void k_reduce(const float* __restrict__ part,
                                                float* __restrict__ out)
{
    const int rb  = blockIdx.x;
    const int col = threadIdx.x & 63;
    const int r0  = threadIdx.x >> 6;
    #pragma unroll
    for (int rr = 0; rr < 4; ++rr) {
        const int r   = rb * 16 + r0 * 4 + rr;
        const int rtr = r >> 6;
        const int rl  = r & 63;
        float h = 0.f, l = 0.f;
        #pragma unroll
        for (int js = 0; js < 8; ++js) {
            const float* pbase =
                part + ((size_t)(js * 128 + rtr) * 64 + rl) * PROW;
            h += pbase[col];
            l += pbase[64];
        }
        float v = h / l;
        out[(size_t)r * FF + col] = (v > 0.f) ? v : (__expf(v) - 1.0f);
    }
}

extern "C" void kernel_launch(void* const* d_in, const int* in_sizes, int n_in,
                              void* d_out, int out_size, void* d_ws, size_t ws_size,
                              hipStream_t stream)
{
    const float* inp = (const float*)d_in[0];
    const int*   adj = (const int*)d_in[1];
    const float* W   = (const float*)d_in[2];
    const float* a   = (const float*)d_in[3];
    float* out = (float*)d_out;

    char* ws = (char*)d_ws;
    _Float16* WhT = (_Float16*)ws;                          // 80*NN*2 reserved
    float* s    = (float*)(ws + (size_t)80 * NN * 2);
    float* d    = s + NN;
    float* dmp  = d + NN;
    _Float16* afac = (_Float16*)(dmp + 512);
    _Float16* cfac = afac + NN;
    _Float16* bfac = cfac + NN;
    _Float16* dfac = bfac + NN;
    float* part = (float*)(dfac + NN);                      // 1024*64*66*4 = 17.3 MB
    unsigned char* mask = (unsigned char*)(part + (size_t)1024 * 64 * PROW);  // 67 MB

    k_pack  <<<(size_t)NN * NN / 8 / 256, 256, 0, stream>>>(adj, mask);
    k_prep  <<<NN / 16, 256, 0, stream>>>(inp, W, a, WhT, s, d, dmp);
    k_vec   <<<NN / 256, 256, 0, stream>>>(s, d, dmp, afac, cfac, bfac, dfac);
    k_main  <<<128 * JSPLIT, 256, 0, stream>>>(mask, WhT, afac, cfac, bfac, dfac, part);
    k_reduce<<<NN / 16, 256, 0, stream>>>(part, out);
}

// Round 9
// 386.639 us; speedup vs baseline: 1.0281x; 1.0281x over previous
//
#include <hip/hip_runtime.h>
#include <hip/hip_bf16.h>

#define NN 8192
#define FF 64
#define JSPLIT 8
#define JRANGE (NN / JSPLIT)    // 1024 cols per block
#define JT 64                   // cols per iteration
#define NIT (JRANGE / JT)       // 16
#define PROW 66                 // partial row stride: H[0..63], l at [64]

// LDS layout (bytes): 3 B-buffers + factors + LUT = 32768
#define B_OFF   0               // 3 x 8192: B tile 64 feats x 128 B (swizzled)
#define FAC_OFF 24576           // bfac 2048 B | dfac 2048 B (js window)
#define LUT_OFF 28672           // 256 x 16 B bit->fp16-mask LUT

typedef _Float16 half8 __attribute__((ext_vector_type(8)));
typedef _Float16 half4v __attribute__((ext_vector_type(4)));
typedef _Float16 half2v __attribute__((ext_vector_type(2)));
typedef float f32x4 __attribute__((ext_vector_type(4)));
typedef int i32x4 __attribute__((ext_vector_type(4)));

__device__ __forceinline__ void async16(const void* g, void* l)
{
    __builtin_amdgcn_global_load_lds(
        (const __attribute__((address_space(1))) unsigned int*)g,
        (__attribute__((address_space(3))) unsigned int*)l, 16, 0, 0);
}

// ---------------------------------------------------------------------------
// Kernel 0: adj -> lane-transposed bit-mask (8 MB).
// Layout: mask2[row][js][cc][g][it]  (byte index it in 0..15, uint4 per lane)
// Thread = (row, js, cc, g): reads 16 x 32 B, writes one uint4.
// ---------------------------------------------------------------------------
__global__ __launch_bounds__(256) void k_pack(const int* __restrict__ adj,
                                              unsigned char* __restrict__ mask2)
{
    const int tid  = threadIdx.x;
    const int row  = blockIdx.x * 4 + (tid >> 6);
    const int lane = tid & 63;
    const int js = lane >> 3, cc = (lane >> 2) & 1, g = lane & 3;
    const int* src = adj + (size_t)row * NN + js * 1024 + cc * 32 + g * 8;

    unsigned ow[4];
    #pragma unroll
    for (int w = 0; w < 4; ++w) {
        unsigned o = 0;
        #pragma unroll
        for (int h = 0; h < 4; ++h) {
            const int it = w * 4 + h;
            i32x4 a = __builtin_nontemporal_load((const i32x4*)(src + it * 64));
            i32x4 b = __builtin_nontemporal_load((const i32x4*)(src + it * 64 + 4));
            unsigned by = 0;
            by |= (a[0] > 0) ? 1u   : 0u;
            by |= (a[1] > 0) ? 2u   : 0u;
            by |= (a[2] > 0) ? 4u   : 0u;
            by |= (a[3] > 0) ? 8u   : 0u;
            by |= (b[0] > 0) ? 16u  : 0u;
            by |= (b[1] > 0) ? 32u  : 0u;
            by |= (b[2] > 0) ? 64u  : 0u;
            by |= (b[3] > 0) ? 128u : 0u;
            o |= by << (h * 8);
        }
        ow[w] = o;
    }
    uint4 v; v.x = ow[0]; v.y = ow[1]; v.z = ow[2]; v.w = ow[3];
    *(uint4*)(mask2 + (size_t)row * 1024 + js * 128 + cc * 64 + g * 16) = v;
}

// ---------------------------------------------------------------------------
// Kernel 1: Wh = inputs @ W; s = Wh@a_src; d = Wh@a_dst; WhT fp16 (64 x NN);
// per-block max(d) partial.
// ---------------------------------------------------------------------------
__global__ __launch_bounds__(256) void k_prep(const float* __restrict__ inp,
                                              const float* __restrict__ W,
                                              const float* __restrict__ a,
                                              _Float16* __restrict__ WhT,
                                              float* __restrict__ s,
                                              float* __restrict__ d,
                                              float* __restrict__ dmax_part)
{
    __shared__ float Wl[64][64];
    __shared__ float asrc[64], adst[64];
    __shared__ _Float16 tr[64][20];
    __shared__ float dmx[16];
    const int t = threadIdx.x;
    for (int idx = t; idx < 4096; idx += 256) Wl[idx >> 6][idx & 63] = W[idx];
    if (t < 64) { asrc[t] = a[t]; adst[t] = a[64 + t]; }
    __syncthreads();

    const int rowl = t >> 4;
    const int fg   = t & 15;
    const int row  = blockIdx.x * 16 + rowl;
    const float* ip = inp + (size_t)row * FF;

    float a0 = 0.f, a1 = 0.f, a2 = 0.f, a3 = 0.f;
    #pragma unroll
    for (int k4 = 0; k4 < 16; ++k4) {
        float4 x  = *(const float4*)(ip + k4 * 4);
        float4 w0 = *(const float4*)&Wl[k4 * 4 + 0][fg * 4];
        float4 w1 = *(const float4*)&Wl[k4 * 4 + 1][fg * 4];
        float4 w2 = *(const float4*)&Wl[k4 * 4 + 2][fg * 4];
        float4 w3 = *(const float4*)&Wl[k4 * 4 + 3][fg * 4];
        a0 += x.x * w0.x + x.y * w1.x + x.z * w2.x + x.w * w3.x;
        a1 += x.x * w0.y + x.y * w1.y + x.z * w2.y + x.w * w3.y;
        a2 += x.x * w0.z + x.y * w1.z + x.z * w2.z + x.w * w3.z;
        a3 += x.x * w0.w + x.y * w1.w + x.z * w2.w + x.w * w3.w;
    }

    float sp = a0 * asrc[fg*4] + a1 * asrc[fg*4+1] + a2 * asrc[fg*4+2] + a3 * asrc[fg*4+3];
    float dp = a0 * adst[fg*4] + a1 * adst[fg*4+1] + a2 * adst[fg*4+2] + a3 * adst[fg*4+3];
    #pragma unroll
    for (int msk = 1; msk < 16; msk <<= 1) {
        sp += __shfl_xor(sp, msk);
        dp += __shfl_xor(dp, msk);
    }
    if (fg == 0) { s[row] = sp; d[row] = dp; dmx[rowl] = dp; }

    tr[fg * 4 + 0][rowl] = (_Float16)a0;
    tr[fg * 4 + 1][rowl] = (_Float16)a1;
    tr[fg * 4 + 2][rowl] = (_Float16)a2;
    tr[fg * 4 + 3][rowl] = (_Float16)a3;
    __syncthreads();
    {
        const int f = t >> 2, seg = t & 3;
        *(half4v*)(WhT + (size_t)f * NN + blockIdx.x * 16 + seg * 4) =
            *(const half4v*)&tr[f][seg * 4];
    }
    if (t == 0) {
        float mm = dmx[0];
        #pragma unroll
        for (int i = 1; i < 16; ++i) mm = fmaxf(mm, dmx[i]);
        dmax_part[blockIdx.x] = mm;
    }
}

// ---------------------------------------------------------------------------
// Kernel 2: dmax; separable softmax factors (all <= 1, fp16-safe).
// ---------------------------------------------------------------------------
__global__ __launch_bounds__(256) void k_vec(const float* __restrict__ s,
                                             const float* __restrict__ d,
                                             const float* __restrict__ dmax_part,
                                             _Float16* __restrict__ afac,
                                             _Float16* __restrict__ cfac,
                                             _Float16* __restrict__ bfac,
                                             _Float16* __restrict__ dfac)
{
    __shared__ float red[256];
    const int t = threadIdx.x;
    float m = fmaxf(dmax_part[t], dmax_part[t + 256]);
    red[t] = m;
    __syncthreads();
    for (int off = 128; off > 0; off >>= 1) {
        if (t < off) red[t] = fmaxf(red[t], red[t + off]);
        __syncthreads();
    }
    const float dmax = red[0];
    const int row = blockIdx.x * 256 + t;
    const float x = s[row] + dmax;
    const float c = fmaxf(x, 0.2f * x);
    afac[row] = (_Float16)__expf(x - c);
    cfac[row] = (_Float16)__expf(0.2f * x - c);
    const float y = d[row] - dmax;
    bfac[row] = (_Float16)__expf(y);
    dfac[row] = (_Float16)__expf(0.2f * y);
}

// ---------------------------------------------------------------------------
// Kernel 3 (main): 1024 blocks = 128 row-tiles(64 rows) x 8 j-splits, 4/CU.
// Mask in VGPRs (one-shot), factors in LDS (one-shot), LUT in LDS. Loop only
// stages B: 2 async16/wave/iter, 3 buffers, prefetch distance 2, vmcnt(2),
// ONE barrier per iter. Hot loop: no exp, no global loads except B DMA.
// ---------------------------------------------------------------------------
__global__ __launch_bounds__(256, 4) void k_main(const unsigned char* __restrict__ mask2,
                                                 const _Float16* __restrict__ WhT,
                                                 const _Float16* __restrict__ afac,
                                                 const _Float16* __restrict__ cfac,
                                                 const _Float16* __restrict__ bfac,
                                                 const _Float16* __restrict__ dfac,
                                                 float* __restrict__ part)
{
    __shared__ __align__(16) unsigned char sm[32768];

    const int tid  = threadIdx.x;
    const int wv   = tid >> 6;
    const int lane = tid & 63;
    const int mrow = lane & 15;
    const int g    = lane >> 4;        // 0..3
    const int rt   = blockIdx.x & 127;
    const int js   = blockIdx.x >> 7;
    const int i0   = rt * 64;
    const int j0base = js * JRANGE;
    const int arow = i0 + wv * 16 + mrow;

    // ---- LUT: byte -> 8 fp16 AND-masks (uint4), built by all 256 threads
    {
        const unsigned t = tid;
        uint4 e;
        e.x = ((t & 1u)   ? 0xFFFFu : 0u) | ((t & 2u)   ? 0xFFFF0000u : 0u);
        e.y = ((t & 4u)   ? 0xFFFFu : 0u) | ((t & 8u)   ? 0xFFFF0000u : 0u);
        e.z = ((t & 16u)  ? 0xFFFFu : 0u) | ((t & 32u)  ? 0xFFFF0000u : 0u);
        e.w = ((t & 64u)  ? 0xFFFFu : 0u) | ((t & 128u) ? 0xFFFF0000u : 0u);
        *(uint4*)&sm[LUT_OFF + tid * 16] = e;
    }

    // ---- per-lane mask for the whole block: 2 x uint4 straight to VGPRs
    unsigned mw[2][4];
    {
        uint4 m0 = *(const uint4*)(mask2 + (size_t)arow * 1024 + js * 128 + g * 16);
        uint4 m1 = *(const uint4*)(mask2 + (size_t)arow * 1024 + js * 128 + 64 + g * 16);
        mw[0][0] = m0.x; mw[0][1] = m0.y; mw[0][2] = m0.z; mw[0][3] = m0.w;
        mw[1][0] = m1.x; mw[1][1] = m1.y; mw[1][2] = m1.z; mw[1][3] = m1.w;
    }

    // ---- per-row factors (uniform within lane)
    union { _Float16 h[2]; unsigned u; half2v v; } ua, uc;
    ua.h[0] = afac[arow]; ua.h[1] = ua.h[0];
    uc.h[0] = cfac[arow]; uc.h[1] = uc.h[0];
    const half2v a2 = ua.v, c2 = uc.v;

    f32x4 acc[5];
    #pragma unroll
    for (int n = 0; n < 5; ++n) acc[n] = (f32x4){0.f, 0.f, 0.f, 0.f};

    // stage B tile for iter it into buffer it%3: 2 async16 per wave,
    // XOR-swizzled on the global side (reader un-swizzles) for bank spread.
    auto stageB = [&](int it) {
        const int j0 = j0base + it * JT;
        unsigned char* base = &sm[B_OFF + (it % 3) * 8192];
        #pragma unroll
        for (int qq = 0; qq < 2; ++qq) {
            const int q  = wv * 2 + qq;
            const int f  = q * 8 + (lane >> 3);
            const int sw = (lane & 7) ^ (lane >> 3);
            async16(WhT + (size_t)f * NN + j0 + sw * 8,
                    base + q * 1024 + lane * 16);
        }
    };

    // ---- prologue: factors (1 async16/wave) + tiles 0,1
    {
        const _Float16* fsrc = (wv < 2)
            ? (bfac + j0base + wv * 512 + lane * 8)
            : (dfac + j0base + (wv - 2) * 512 + lane * 8);
        async16(fsrc, &sm[FAC_OFF + wv * 1024 + lane * 16]);
    }
    stageB(0);
    stageB(1);
    asm volatile("s_waitcnt lgkmcnt(0)" ::: "memory");   // LUT writes done

    const half8 ones = {(_Float16)1.f, (_Float16)1.f, (_Float16)1.f, (_Float16)1.f,
                        (_Float16)1.f, (_Float16)1.f, (_Float16)1.f, (_Float16)1.f};
    const int r7 = mrow & 7;
    const int qh = mrow >> 3;

    #pragma unroll
    for (int it = 0; it < NIT; ++it) {
        // drain tile(it) (+factors at it=0); tile(it+1) stays in flight
        if (it < NIT - 1)
            asm volatile("s_waitcnt vmcnt(2)" ::: "memory");
        else
            asm volatile("s_waitcnt vmcnt(0)" ::: "memory");
        __builtin_amdgcn_s_barrier();     // tile(it) visible; prev reads done
        asm volatile("" ::: "memory");

        if (it + 2 < NIT) stageB(it + 2); // prefetch (overwrites buf read at it-1)

        const unsigned char* bb = &sm[B_OFF + (it % 3) * 8192];

        #pragma unroll
        for (int cc = 0; cc < 2; ++cc) {
            const unsigned bt = (mw[cc][it >> 2] >> ((it & 3) * 8)) & 0xffu;
            uint4 bm = *(const uint4*)&sm[LUT_OFF + bt * 16];
            const int colb = (it * 64 + cc * 32 + g * 8) * 2;
            uint4 bv4 = *(const uint4*)&sm[FAC_OFF + colb];
            uint4 dv4 = *(const uint4*)&sm[FAC_OFF + 2048 + colb];

            union { unsigned u[4]; half8 h; } af;
            #pragma unroll
            for (int k = 0; k < 4; ++k) {
                union { unsigned u; half2v v; } b2, d2, pm;
                b2.u = (&bv4.x)[k];
                d2.u = (&dv4.x)[k];
                pm.v = __builtin_elementwise_max(a2 * b2.v, c2 * d2.v);
                af.u[k] = pm.u & (&bm.x)[k];
            }

            #pragma unroll
            for (int n = 0; n < 4; ++n) {
                const int q = n * 2 + qh;
                half8 B = *(const half8*)&bb[q * 1024 + r7 * 128 +
                                             (((cc * 4 + g) ^ r7) * 16)];
                acc[n] = __builtin_amdgcn_mfma_f32_16x16x32_f16(af.h, B, acc[n], 0, 0, 0);
            }
            acc[4] = __builtin_amdgcn_mfma_f32_16x16x32_f16(af.h, ones, acc[4], 0, 0, 0);
        }
    }

    // ---- epilogue: per-wave rows ----
    float* pb = part + (size_t)blockIdx.x * (64 * PROW) + wv * 16 * PROW;
    #pragma unroll
    for (int n = 0; n < 4; ++n)
        #pragma unroll
        for (int r = 0; r < 4; ++r)
            pb[(g * 4 + r) * PROW + n * 16 + mrow] = acc[n][r];
    if (mrow == 0) {
        #pragma unroll
        for (int r = 0; r < 4; ++r)
            pb[(g * 4 + r) * PROW + 64] = acc[4][r];
    }
}

// ---------------------------------------------------------------------------
// Kernel 4: combine 8 j-split partials, divide by l, ELU, write out.
// ---------------------------------------------------------------------------
__global__ __launch_bounds__(256) void k_reduce(const float* __restrict__ part,
                                                float* __restrict__ out)
{
    const int rb  = blockIdx.x;
    const int col = threadIdx.x & 63;
    const int r0  = threadIdx.x >> 6;
    #pragma unroll
    for (int rr = 0; rr < 4; ++rr) {
        const int r   = rb * 16 + r0 * 4 + rr;
        const int rtr = r >> 6;
        const int rl  = r & 63;
        float h = 0.f, l = 0.f;
        #pragma unroll
        for (int js = 0; js < 8; ++js) {
            const float* pbase =
                part + ((size_t)(js * 128 + rtr) * 64 + rl) * PROW;
            h += pbase[col];
            l += pbase[64];
        }
        float v = h / l;
        out[(size_t)r * FF + col] = (v > 0.f) ? v : (__expf(v) - 1.0f);
    }
}

extern "C" void kernel_launch(void* const* d_in, const int* in_sizes, int n_in,
                              void* d_out, int out_size, void* d_ws, size_t ws_size,
                              hipStream_t stream)
{
    const float* inp = (const float*)d_in[0];
    const int*   adj = (const int*)d_in[1];
    const float* W   = (const float*)d_in[2];
    const float* a   = (const float*)d_in[3];
    float* out = (float*)d_out;

    char* ws = (char*)d_ws;
    _Float16* WhT = (_Float16*)ws;                          // 80*NN*2 reserved
    float* s    = (float*)(ws + (size_t)80 * NN * 2);
    float* d    = s + NN;
    float* dmp  = d + NN;
    _Float16* afac = (_Float16*)(dmp + 512);
    _Float16* cfac = afac + NN;
    _Float16* bfac = cfac + NN;
    _Float16* dfac = bfac + NN;
    float* part = (float*)(dfac + NN);                      // 1024*64*66*4 = 17.3 MB
    unsigned char* mask2 = (unsigned char*)(part + (size_t)1024 * 64 * PROW);  // 8 MB

    k_pack  <<<NN / 4, 256, 0, stream>>>(adj, mask2);
    k_prep  <<<NN / 16, 256, 0, stream>>>(inp, W, a, WhT, s, d, dmp);
    k_vec   <<<NN / 256, 256, 0, stream>>>(s, d, dmp, afac, cfac, bfac, dfac);
    k_main  <<<128 * JSPLIT, 256, 0, stream>>>(mask2, WhT, afac, cfac, bfac, dfac, part);
    k_reduce<<<NN / 16, 256, 0, stream>>>(part, out);
}

// Round 10
// 386.325 us; speedup vs baseline: 1.0290x; 1.0008x over previous
//
#include <hip/hip_runtime.h>
#include <hip/hip_bf16.h>

#define NN 8192
#define FF 64
#define JSPLIT 16
#define JRANGE (NN / JSPLIT)    // 512 cols per block
#define JT 64                   // cols per iteration
#define NIT (JRANGE / JT)       // 8
#define PROW 66                 // partial row stride: H[0..63], l at [64]

// LDS (bytes): 4 B-buffers + factor window = 36864
#define B_OFF   0               // 4 x 8192: B tile 64 feats x 128 B (swizzled)
#define FAC_OFF 32768           // bfac 1024 | dfac 1024 | dup 2048
#define LDS_SZ  36864

typedef _Float16 half8 __attribute__((ext_vector_type(8)));
typedef _Float16 half4v __attribute__((ext_vector_type(4)));
typedef _Float16 half2v __attribute__((ext_vector_type(2)));
typedef float f32x4 __attribute__((ext_vector_type(4)));
typedef int i32x4 __attribute__((ext_vector_type(4)));

__device__ __forceinline__ void async16(const void* g, void* l)
{
    __builtin_amdgcn_global_load_lds(
        (const __attribute__((address_space(1))) unsigned int*)g,
        (__attribute__((address_space(3))) unsigned int*)l, 16, 0, 0);
}

// ---------------------------------------------------------------------------
// Kernel 0: adj -> bit-mask, layout mask2[row][js16][cc][g][it8] (1024 B/row).
// Thread = (row, js, cc, g): reads 8 x 32 B, writes one uint2 (its 0..7).
// ---------------------------------------------------------------------------
__global__ __launch_bounds__(256) void k_pack(const int* __restrict__ adj,
                                              unsigned char* __restrict__ mask2)
{
    const int tid = threadIdx.x;
    const int row = blockIdx.x * 2 + (tid >> 7);
    const int l7  = tid & 127;
    const int js = l7 >> 3, cc = (l7 >> 2) & 1, g = l7 & 3;
    const int* src = adj + (size_t)row * NN + js * JRANGE + cc * 32 + g * 8;

    unsigned ow[2];
    #pragma unroll
    for (int w = 0; w < 2; ++w) {
        unsigned o = 0;
        #pragma unroll
        for (int h = 0; h < 4; ++h) {
            const int it = w * 4 + h;
            i32x4 a = __builtin_nontemporal_load((const i32x4*)(src + it * 64));
            i32x4 b = __builtin_nontemporal_load((const i32x4*)(src + it * 64 + 4));
            unsigned by = 0;
            by |= (a[0] > 0) ? 1u   : 0u;
            by |= (a[1] > 0) ? 2u   : 0u;
            by |= (a[2] > 0) ? 4u   : 0u;
            by |= (a[3] > 0) ? 8u   : 0u;
            by |= (b[0] > 0) ? 16u  : 0u;
            by |= (b[1] > 0) ? 32u  : 0u;
            by |= (b[2] > 0) ? 64u  : 0u;
            by |= (b[3] > 0) ? 128u : 0u;
            o |= by << (h * 8);
        }
        ow[w] = o;
    }
    uint2 v; v.x = ow[0]; v.y = ow[1];
    *(uint2*)(mask2 + (size_t)row * 1024 + js * 64 + cc * 32 + g * 8) = v;
}

// ---------------------------------------------------------------------------
// Kernel 1: Wh = inputs @ W; s, d; WhT fp16 (64 x NN); per-block max(d).
// ---------------------------------------------------------------------------
__global__ __launch_bounds__(256) void k_prep(const float* __restrict__ inp,
                                              const float* __restrict__ W,
                                              const float* __restrict__ a,
                                              _Float16* __restrict__ WhT,
                                              float* __restrict__ s,
                                              float* __restrict__ d,
                                              float* __restrict__ dmax_part)
{
    __shared__ float Wl[64][64];
    __shared__ float asrc[64], adst[64];
    __shared__ _Float16 tr[64][20];
    __shared__ float dmx[16];
    const int t = threadIdx.x;
    for (int idx = t; idx < 4096; idx += 256) Wl[idx >> 6][idx & 63] = W[idx];
    if (t < 64) { asrc[t] = a[t]; adst[t] = a[64 + t]; }
    __syncthreads();

    const int rowl = t >> 4;
    const int fg   = t & 15;
    const int row  = blockIdx.x * 16 + rowl;
    const float* ip = inp + (size_t)row * FF;

    float a0 = 0.f, a1 = 0.f, a2 = 0.f, a3 = 0.f;
    #pragma unroll
    for (int k4 = 0; k4 < 16; ++k4) {
        float4 x  = *(const float4*)(ip + k4 * 4);
        float4 w0 = *(const float4*)&Wl[k4 * 4 + 0][fg * 4];
        float4 w1 = *(const float4*)&Wl[k4 * 4 + 1][fg * 4];
        float4 w2 = *(const float4*)&Wl[k4 * 4 + 2][fg * 4];
        float4 w3 = *(const float4*)&Wl[k4 * 4 + 3][fg * 4];
        a0 += x.x * w0.x + x.y * w1.x + x.z * w2.x + x.w * w3.x;
        a1 += x.x * w0.y + x.y * w1.y + x.z * w2.y + x.w * w3.y;
        a2 += x.x * w0.z + x.y * w1.z + x.z * w2.z + x.w * w3.z;
        a3 += x.x * w0.w + x.y * w1.w + x.z * w2.w + x.w * w3.w;
    }

    float sp = a0 * asrc[fg*4] + a1 * asrc[fg*4+1] + a2 * asrc[fg*4+2] + a3 * asrc[fg*4+3];
    float dp = a0 * adst[fg*4] + a1 * adst[fg*4+1] + a2 * adst[fg*4+2] + a3 * adst[fg*4+3];
    #pragma unroll
    for (int msk = 1; msk < 16; msk <<= 1) {
        sp += __shfl_xor(sp, msk);
        dp += __shfl_xor(dp, msk);
    }
    if (fg == 0) { s[row] = sp; d[row] = dp; dmx[rowl] = dp; }

    tr[fg * 4 + 0][rowl] = (_Float16)a0;
    tr[fg * 4 + 1][rowl] = (_Float16)a1;
    tr[fg * 4 + 2][rowl] = (_Float16)a2;
    tr[fg * 4 + 3][rowl] = (_Float16)a3;
    __syncthreads();
    {
        const int f = t >> 2, seg = t & 3;
        *(half4v*)(WhT + (size_t)f * NN + blockIdx.x * 16 + seg * 4) =
            *(const half4v*)&tr[f][seg * 4];
    }
    if (t == 0) {
        float mm = dmx[0];
        #pragma unroll
        for (int i = 1; i < 16; ++i) mm = fmaxf(mm, dmx[i]);
        dmax_part[blockIdx.x] = mm;
    }
}

// ---------------------------------------------------------------------------
// Kernel 2: dmax; separable softmax factors (all <= 1, fp16-safe).
// ---------------------------------------------------------------------------
__global__ __launch_bounds__(256) void k_vec(const float* __restrict__ s,
                                             const float* __restrict__ d,
                                             const float* __restrict__ dmax_part,
                                             _Float16* __restrict__ afac,
                                             _Float16* __restrict__ cfac,
                                             _Float16* __restrict__ bfac,
                                             _Float16* __restrict__ dfac)
{
    __shared__ float red[256];
    const int t = threadIdx.x;
    float m = fmaxf(dmax_part[t], dmax_part[t + 256]);
    red[t] = m;
    __syncthreads();
    for (int off = 128; off > 0; off >>= 1) {
        if (t < off) red[t] = fmaxf(red[t], red[t + off]);
        __syncthreads();
    }
    const float dmax = red[0];
    const int row = blockIdx.x * 256 + t;
    const float x = s[row] + dmax;
    const float c = fmaxf(x, 0.2f * x);
    afac[row] = (_Float16)__expf(x - c);
    cfac[row] = (_Float16)__expf(0.2f * x - c);
    const float y = d[row] - dmax;
    bfac[row] = (_Float16)__expf(y);
    dfac[row] = (_Float16)__expf(0.2f * y);
}

// ---------------------------------------------------------------------------
// Kernel 3 (main): 1024 blocks = 64 row-tiles(128 rows) x 16 j-splits, 4/CU.
// Each wave owns 32 rows (2 A-frags) -> B LDS reads amortized 2x. Bit-mask in
// VGPRs, expanded by VALU (no LUT gather). 4 B-buffers, prefetch distance 2,
// vmcnt(2), ONE barrier per iter. No exp, no global loads in loop except DMA.
// ---------------------------------------------------------------------------
__global__ __launch_bounds__(256, 4) void k_main(const unsigned char* __restrict__ mask2,
                                                 const _Float16* __restrict__ WhT,
                                                 const _Float16* __restrict__ afac,
                                                 const _Float16* __restrict__ cfac,
                                                 const _Float16* __restrict__ bfac,
                                                 const _Float16* __restrict__ dfac,
                                                 float* __restrict__ part)
{
    __shared__ __align__(16) unsigned char sm[LDS_SZ];

    const int tid  = threadIdx.x;
    const int wv   = tid >> 6;
    const int lane = tid & 63;
    const int mrow = lane & 15;
    const int g    = lane >> 4;
    const int rt   = blockIdx.x & 63;
    const int js   = blockIdx.x >> 6;
    const int i0   = rt * 128;
    const int j0base = js * JRANGE;
    const int arow0 = i0 + wv * 32 + mrow;   // row-group 0
    const int arow1 = arow0 + 16;            // row-group 1

    // ---- per-lane bit-masks (uint2 per row per cc), straight to VGPRs
    uint2 mw[2][2];
    {
        const unsigned char* mb0 = mask2 + (size_t)arow0 * 1024 + js * 64 + g * 8;
        const unsigned char* mb1 = mask2 + (size_t)arow1 * 1024 + js * 64 + g * 8;
        mw[0][0] = *(const uint2*)(mb0);
        mw[0][1] = *(const uint2*)(mb0 + 32);
        mw[1][0] = *(const uint2*)(mb1);
        mw[1][1] = *(const uint2*)(mb1 + 32);
    }

    // ---- per-row factors (packed pairs)
    half2v a2[2], c2[2];
    {
        union { _Float16 h[2]; half2v v; } u;
        u.h[0] = afac[arow0]; u.h[1] = u.h[0]; a2[0] = u.v;
        u.h[0] = cfac[arow0]; u.h[1] = u.h[0]; c2[0] = u.v;
        u.h[0] = afac[arow1]; u.h[1] = u.h[0]; a2[1] = u.v;
        u.h[0] = cfac[arow1]; u.h[1] = u.h[0]; c2[1] = u.v;
    }

    f32x4 acc[2][5];
    #pragma unroll
    for (int r = 0; r < 2; ++r)
        #pragma unroll
        for (int n = 0; n < 5; ++n) acc[r][n] = (f32x4){0.f, 0.f, 0.f, 0.f};

    // stage B tile for iter it into buffer it&3 (2 async16/wave, swizzled)
    auto stageB = [&](int it) {
        const int j0 = j0base + it * JT;
        unsigned char* base = &sm[B_OFF + (it & 3) * 8192];
        #pragma unroll
        for (int qq = 0; qq < 2; ++qq) {
            const int q  = wv * 2 + qq;
            const int f  = q * 8 + (lane >> 3);
            const int sw = (lane & 7) ^ (lane >> 3);
            async16(WhT + (size_t)f * NN + j0 + sw * 8,
                    base + q * 1024 + lane * 16);
        }
    };

    // ---- prologue: factor window (1 async16/wave) + tiles 0,1
    {
        const _Float16* fsrc = (wv == 0) ? (bfac + j0base + lane * 8)
                             : (wv == 1) ? (dfac + j0base + lane * 8)
                             : (wv == 2) ? (bfac + j0base + lane * 8)
                                         : (dfac + j0base + lane * 8);
        const int dst = (wv == 0) ? 0 : (wv == 1) ? 1024 : 2048 + (wv - 2) * 1024;
        async16(fsrc, &sm[FAC_OFF + dst + lane * 16]);
    }
    stageB(0);
    stageB(1);

    const half8 ones = {(_Float16)1.f, (_Float16)1.f, (_Float16)1.f, (_Float16)1.f,
                        (_Float16)1.f, (_Float16)1.f, (_Float16)1.f, (_Float16)1.f};
    const int r7 = mrow & 7;
    const int qh = mrow >> 3;

    #pragma unroll
    for (int it = 0; it < NIT; ++it) {
        if (it < NIT - 1)
            asm volatile("s_waitcnt vmcnt(2)" ::: "memory");  // tile(it) landed
        else
            asm volatile("s_waitcnt vmcnt(0)" ::: "memory");
        __builtin_amdgcn_s_barrier();
        asm volatile("" ::: "memory");

        if (it + 2 < NIT) stageB(it + 2);                     // prefetch

        const unsigned char* bb = &sm[B_OFF + (it & 3) * 8192];

        #pragma unroll
        for (int cc = 0; cc < 2; ++cc) {
            const int colb = (it * 64 + cc * 32 + g * 8) * 2;
            uint4 bv4 = *(const uint4*)&sm[FAC_OFF + colb];
            uint4 dv4 = *(const uint4*)&sm[FAC_OFF + 1024 + colb];

            union { unsigned u[4]; half8 h; } af[2];
            #pragma unroll
            for (int r = 0; r < 2; ++r) {
                const unsigned w  = (it < 4) ? mw[r][cc].x : mw[r][cc].y;
                const unsigned bt = (w >> ((it & 3) * 8)) & 0xffu;
                #pragma unroll
                for (int k = 0; k < 4; ++k) {
                    union { unsigned u; half2v v; } b2, d2, pm;
                    b2.u = (&bv4.x)[k];
                    d2.u = (&dv4.x)[k];
                    pm.v = __builtin_elementwise_max(a2[r] * b2.v, c2[r] * d2.v);
                    const unsigned lo = ((bt >> (2 * k)) & 1u) * 0xFFFFu;
                    const unsigned hi = ((bt >> (2 * k + 1)) & 1u) * 0xFFFF0000u;
                    af[r].u[k] = pm.u & (lo | hi);
                }
            }

            #pragma unroll
            for (int n = 0; n < 4; ++n) {
                const int q = n * 2 + qh;
                half8 B = *(const half8*)&bb[q * 1024 + r7 * 128 +
                                             (((cc * 4 + g) ^ r7) * 16)];
                acc[0][n] = __builtin_amdgcn_mfma_f32_16x16x32_f16(af[0].h, B, acc[0][n], 0, 0, 0);
                acc[1][n] = __builtin_amdgcn_mfma_f32_16x16x32_f16(af[1].h, B, acc[1][n], 0, 0, 0);
            }
            acc[0][4] = __builtin_amdgcn_mfma_f32_16x16x32_f16(af[0].h, ones, acc[0][4], 0, 0, 0);
            acc[1][4] = __builtin_amdgcn_mfma_f32_16x16x32_f16(af[1].h, ones, acc[1][4], 0, 0, 0);
        }
    }

    // ---- epilogue: rows i = wv*32 + r*16 + (g*4+reg); col = n*16+mrow ----
    float* pb = part + (size_t)blockIdx.x * (128 * PROW) + wv * 32 * PROW;
    #pragma unroll
    for (int r = 0; r < 2; ++r) {
        #pragma unroll
        for (int n = 0; n < 4; ++n)
            #pragma unroll
            for (int reg = 0; reg < 4; ++reg)
                pb[(r * 16 + g * 4 + reg) * PROW + n * 16 + mrow] = acc[r][n][reg];
        if (mrow == 0) {
            #pragma unroll
            for (int reg = 0; reg < 4; ++reg)
                pb[(r * 16 + g * 4 + reg) * PROW + 64] = acc[r][4][reg];
        }
    }
}

// ---------------------------------------------------------------------------
// Kernel 4: combine 16 j-split partials, divide by l, ELU, write out.
// ---------------------------------------------------------------------------
__global__ __launch_bounds__(256) void k_reduce(const float* __restrict__ part,
                                                float* __restrict__ out)
{
    const int rb  = blockIdx.x;
    const int col = threadIdx.x & 63;
    const int r0  = threadIdx.x >> 6;
    #pragma unroll
    for (int rr = 0; rr < 4; ++rr) {
        const int r   = rb * 16 + r0 * 4 + rr;
        const int rtr = r >> 7;
        const int rl  = r & 127;
        float h = 0.f, l = 0.f;
        #pragma unroll
        for (int js = 0; js < JSPLIT; ++js) {
            const float* pbase =
                part + ((size_t)(js * 64 + rtr) * 128 + rl) * PROW;
            h += pbase[col];
            l += pbase[64];
        }
        float v = h / l;
        out[(size_t)r * FF + col] = (v > 0.f) ? v : (__expf(v) - 1.0f);
    }
}

extern "C" void kernel_launch(void* const* d_in, const int* in_sizes, int n_in,
                              void* d_out, int out_size, void* d_ws, size_t ws_size,
                              hipStream_t stream)
{
    const float* inp = (const float*)d_in[0];
    const int*   adj = (const int*)d_in[1];
    const float* W   = (const float*)d_in[2];
    const float* a   = (const float*)d_in[3];
    float* out = (float*)d_out;

    char* ws = (char*)d_ws;
    _Float16* WhT = (_Float16*)ws;                          // 80*NN*2 reserved
    float* s    = (float*)(ws + (size_t)80 * NN * 2);
    float* d    = s + NN;
    float* dmp  = d + NN;
    _Float16* afac = (_Float16*)(dmp + 512);
    _Float16* cfac = afac + NN;
    _Float16* bfac = cfac + NN;
    _Float16* dfac = bfac + NN;
    float* part = (float*)(dfac + NN);                      // 1024*128*66*4 = 34.6 MB
    unsigned char* mask2 = (unsigned char*)(part + (size_t)1024 * 128 * PROW);  // 8 MB

    k_pack  <<<NN / 2, 256, 0, stream>>>(adj, mask2);
    k_prep  <<<NN / 16, 256, 0, stream>>>(inp, W, a, WhT, s, d, dmp);
    k_vec   <<<NN / 256, 256, 0, stream>>>(s, d, dmp, afac, cfac, bfac, dfac);
    k_main  <<<64 * JSPLIT, 256, 0, stream>>>(mask2, WhT, afac, cfac, bfac, dfac, part);
    k_reduce<<<NN / 16, 256, 0, stream>>>(part, out);
}